// Round 1
// 559.897 us; speedup vs baseline: 1.8108x; 1.8108x over previous
//
#include <hip/hip_runtime.h>

#define LEAKY 0.2f

// ---------- helpers ----------
__device__ __forceinline__ float h2f(unsigned short b) {
    union { unsigned short u; _Float16 h; } c; c.u = b; return (float)c.h;
}
__device__ __forceinline__ unsigned short f2h(float f) {
    union { unsigned short u; _Float16 h; } c; c.h = (_Float16)f; return c.u;
}
__device__ __forceinline__ void h4(uint2 w, float& a, float& b, float& c, float& d) {
    a = h2f((unsigned short)(w.x & 0xFFFF)); b = h2f((unsigned short)(w.x >> 16));
    c = h2f((unsigned short)(w.y & 0xFFFF)); d = h2f((unsigned short)(w.y >> 16));
}
__device__ __forceinline__ int clampi(int v, int hi) { return v < 0 ? 0 : (v > hi ? hi : v); }
__device__ __forceinline__ int ld_idx(const int* __restrict__ ei, int is64, size_t pos) {
    return is64 ? ei[pos * 2] : ei[pos];
}

// ---- detect int64 vs int32 edge_index (odd 32-bit words all zero => int64) ----
__global__ __launch_bounds__(256) void detect_kernel(const int* __restrict__ ei, int* flag) {
    __shared__ int nz;
    if (threadIdx.x == 0) nz = 0;
    __syncthreads();
    if (ei[2 * threadIdx.x + 1] != 0) atomicOr(&nz, 1);
    __syncthreads();
    if (threadIdx.x == 0) *flag = (nz == 0) ? 1 : 0;
}

// ---- init: zero degree histogram and CSR fill cursors ----
__global__ __launch_bounds__(256) void init_kernel(int* __restrict__ deg,
                                                   int* __restrict__ cursor, int N) {
    int t = blockIdx.x * 256 + threadIdx.x;
    if (t < N) { deg[t] = 0; cursor[t] = 0; }
}

// ---- 3 GEMMs: x[N,128] f32 @ W[128,128] f32 -> hs fp16, hd f32, hv fp16 ----
__global__ __launch_bounds__(256) void gemm3_kernel(
    const float* __restrict__ x,
    const float* __restrict__ W0, const float* __restrict__ W1, const float* __restrict__ W2,
    unsigned short* __restrict__ o_hs, float* __restrict__ o_hd,
    unsigned short* __restrict__ o_hv, int N)
{
    __shared__ float Ws[128 * 128];  // 64 KB
    __shared__ float Xs[32 * 128];   // 16 KB
    const int t = threadIdx.x;
    const int row0 = blockIdx.x * 32;

    #pragma unroll
    for (int it = 0; it < 4; ++it) {
        int idx = t + it * 256;
        int r = idx >> 5, c = (idx & 31) * 4;
        float4 v = (row0 + r < N) ? *(const float4*)&x[(size_t)(row0 + r) * 128 + c]
                                  : make_float4(0.f, 0.f, 0.f, 0.f);
        *(float4*)&Xs[r * 128 + c] = v;
    }

    const int rg = t >> 5;
    const int cg = t & 31;

    for (int w = 0; w < 3; ++w) {
        const float* Wp = (w == 0) ? W0 : ((w == 1) ? W1 : W2);
        __syncthreads();
        #pragma unroll
        for (int it = 0; it < 16; ++it) {
            int idx = t + it * 256;
            *(float4*)&Ws[idx * 4] = *(const float4*)&Wp[(size_t)idx * 4];
        }
        __syncthreads();

        float acc[4][4] = {};
        for (int k = 0; k < 128; k += 4) {
            float4 a[4], b[4];
            #pragma unroll
            for (int i = 0; i < 4; i++) a[i] = *(const float4*)&Xs[(4 * rg + i) * 128 + k];
            #pragma unroll
            for (int j = 0; j < 4; j++) b[j] = *(const float4*)&Ws[(k + j) * 128 + 4 * cg];
            #pragma unroll
            for (int i = 0; i < 4; i++) {
                acc[i][0] += a[i].x * b[0].x + a[i].y * b[1].x + a[i].z * b[2].x + a[i].w * b[3].x;
                acc[i][1] += a[i].x * b[0].y + a[i].y * b[1].y + a[i].z * b[2].y + a[i].w * b[3].y;
                acc[i][2] += a[i].x * b[0].z + a[i].y * b[1].z + a[i].z * b[2].z + a[i].w * b[3].z;
                acc[i][3] += a[i].x * b[0].w + a[i].y * b[1].w + a[i].z * b[2].w + a[i].w * b[3].w;
            }
        }
        #pragma unroll
        for (int i = 0; i < 4; i++) {
            int gr = row0 + 4 * rg + i;
            if (gr >= N) continue;
            if (w == 1) {
                *(float4*)&o_hd[(size_t)gr * 128 + 4 * cg] =
                    make_float4(acc[i][0], acc[i][1], acc[i][2], acc[i][3]);
            } else {
                unsigned short* o = (w == 0) ? o_hs : o_hv;
                unsigned p0 = f2h(acc[i][0]) | ((unsigned)f2h(acc[i][1]) << 16);
                unsigned p1 = f2h(acc[i][2]) | ((unsigned)f2h(acc[i][3]) << 16);
                *(uint2*)&o[(size_t)gr * 128 + 4 * cg] = make_uint2(p0, p1);
            }
        }
    }
}

// ---- CSR build: histogram of dst ----
__global__ __launch_bounds__(256) void hist_kernel(
    const int* __restrict__ ei, const int* __restrict__ iflag,
    int* __restrict__ deg, int N, int E)
{
    int t = blockIdx.x * 256 + threadIdx.x;
    if (t >= E) return;
    int dst = clampi(ld_idx(ei, *iflag, (size_t)E + t), N - 1);
    atomicAdd(&deg[dst], 1);
}

// ---- multi-block exclusive scan: A) per-block (1024 elems) scan + block sums ----
__global__ __launch_bounds__(256) void scanA_kernel(
    const int* __restrict__ deg, int* __restrict__ offs, int* __restrict__ bsum, int N)
{
    __shared__ int buf[256];
    const int b = blockIdx.x;
    const int t = threadIdx.x;
    const int base = b * 1024 + t * 4;
    int v0 = (base + 0 < N) ? deg[base + 0] : 0;
    int v1 = (base + 1 < N) ? deg[base + 1] : 0;
    int v2 = (base + 2 < N) ? deg[base + 2] : 0;
    int v3 = (base + 3 < N) ? deg[base + 3] : 0;
    int tsum = v0 + v1 + v2 + v3;
    buf[t] = tsum;
    __syncthreads();
    #pragma unroll
    for (int off = 1; off < 256; off <<= 1) {
        int xv = (t >= off) ? buf[t - off] : 0;
        __syncthreads();
        buf[t] += xv;
        __syncthreads();
    }
    int p = buf[t] - tsum;  // exclusive prefix within block
    p += v0; if (base + 0 < N) offs[base + 1] = p;
    p += v1; if (base + 1 < N) offs[base + 2] = p;
    p += v2; if (base + 2 < N) offs[base + 3] = p;
    p += v3; if (base + 3 < N) offs[base + 4] = p;
    if (t == 255) bsum[b] = buf[255];
    if (b == 0 && t == 0) offs[0] = 0;
}

// ---- B) single-block exclusive scan of block sums (NB <= 256) ----
__global__ __launch_bounds__(256) void scanB_kernel(int* __restrict__ bsum, int NB)
{
    __shared__ int buf[256];
    const int t = threadIdx.x;
    int v = (t < NB) ? bsum[t] : 0;
    buf[t] = v;
    __syncthreads();
    #pragma unroll
    for (int off = 1; off < 256; off <<= 1) {
        int xv = (t >= off) ? buf[t - off] : 0;
        __syncthreads();
        buf[t] += xv;
        __syncthreads();
    }
    if (t < NB) bsum[t] = buf[t] - v;  // exclusive
}

// ---- C) add block offsets ----
__global__ __launch_bounds__(256) void scanC_kernel(
    int* __restrict__ offs, const int* __restrict__ bsum, int N)
{
    int i = blockIdx.x * 256 + threadIdx.x;
    if (i < N) offs[i + 1] += bsum[i >> 10];
}

// ---- CSR fill: sorted[offs[dst] + cursor[dst]++] = edge id ----
__global__ __launch_bounds__(256) void fill_kernel(
    const int* __restrict__ ei, const int* __restrict__ iflag,
    const int* __restrict__ offs, int* __restrict__ cursor,
    int* __restrict__ sorted, int N, int E)
{
    int t = blockIdx.x * 256 + threadIdx.x;
    if (t >= E) return;
    int dst = clampi(ld_idx(ei, *iflag, (size_t)E + t), N - 1);
    int pos = offs[dst] + atomicAdd(&cursor[dst], 1);
    sorted[pos] = t;
}

// ---- fused: edge scores + softmax denom + weighted aggregation ----
// One 64-lane wave per dst node. hd[dst] loaded ONCE per wave (was: once per
// edge in edge_score_kernel). Single pass: out = (sum_e exp(s_e)*v_e) / sum_e exp(s_e).
// hd row self-aliases with out row (same wid; read-before-write within the wave).
__global__ __launch_bounds__(256) void gather_fused_kernel(
    const int* __restrict__ ei, const int* __restrict__ iflag,
    const int* __restrict__ offs, const int* __restrict__ sorted,
    const unsigned short* __restrict__ hs, const float* __restrict__ hd,
    const float* __restrict__ av, const unsigned short* __restrict__ hv,
    float* __restrict__ scores, float* __restrict__ out,
    float* __restrict__ segsum, int N, int E)
{
    int wid = (int)(((size_t)blockIdx.x * 256 + threadIdx.x) >> 6);  // dst node
    if (wid >= N) return;
    int lane = threadIdx.x & 63;
    int sub = lane >> 5;   // half-wave 0/1 splits the edge list
    int le = lane & 31;
    int h = le >> 3;
    int is64 = *iflag;
    int beg = offs[wid], end = offs[wid + 1];

    float4 d4 = *(const float4*)&hd[(size_t)wid * 128 + le * 4];
    float4 a4 = *(const float4*)&av[le * 4];

    float sum = 0.f;
    float a0 = 0.f, a1 = 0.f, a2 = 0.f, a3 = 0.f;

    int j = beg + sub;
    int eid = 0, src = 0;
    if (j < end) {
        eid = sorted[j];
        src = clampi(ld_idx(ei, is64, (size_t)eid), N - 1);
    }
    while (j < end) {
        // prefetch next edge's id/src to hide the sorted->ei->gather chain
        int jn = j + 2;
        int eid_n = 0, src_n = 0;
        if (jn < end) {
            eid_n = sorted[jn];
            src_n = clampi(ld_idx(ei, is64, (size_t)eid_n), N - 1);
        }
        uint2 sw = *(const uint2*)&hs[(size_t)src * 128 + le * 4];
        uint2 vw = *(const uint2*)&hv[(size_t)src * 128 + le * 4];
        float s0, s1, s2, s3;
        h4(sw, s0, s1, s2, s3);
        float m, s = 0.f;
        m = s0 + d4.x; m = (m > 0.f) ? m : LEAKY * m; s += m * a4.x;
        m = s1 + d4.y; m = (m > 0.f) ? m : LEAKY * m; s += m * a4.y;
        m = s2 + d4.z; m = (m > 0.f) ? m : LEAKY * m; s += m * a4.z;
        m = s3 + d4.w; m = (m > 0.f) ? m : LEAKY * m; s += m * a4.w;
        s += __shfl_xor(s, 1);
        s += __shfl_xor(s, 2);
        s += __shfl_xor(s, 4);
        if ((le & 7) == 0) scores[(size_t)eid * 4 + h] = s;
        float w = __expf(s);   // |score| << 87, fp32 exp safe without max-shift
        sum += w;
        float v0, v1, v2, v3;
        h4(vw, v0, v1, v2, v3);
        a0 += w * v0; a1 += w * v1; a2 += w * v2; a3 += w * v3;
        j = jn; eid = eid_n; src = src_n;
    }
    sum += __shfl_xor(sum, 32);
    a0 += __shfl_xor(a0, 32); a1 += __shfl_xor(a1, 32);
    a2 += __shfl_xor(a2, 32); a3 += __shfl_xor(a3, 32);
    float inv = 1.f / (sum + 1e-9f);
    if (sub == 0) {
        *(float4*)&out[(size_t)wid * 128 + le * 4] =
            make_float4(a0 * inv, a1 * inv, a2 * inv, a3 * inv);
        if ((le & 7) == 0) segsum[(size_t)wid * 4 + h] = sum;
    }
}

// ---- attn output (coalesced, runs last; overwrites hs/sorted scratch) ----
__global__ __launch_bounds__(256) void attn_write_kernel(
    const int* __restrict__ ei, const int* __restrict__ iflag,
    const float* __restrict__ scores, const float* __restrict__ segsum,
    float* __restrict__ attn_out, int N, int E)
{
    int t = blockIdx.x * 256 + threadIdx.x;
    if (t >= E * 4) return;
    int e = t >> 2, h = t & 3;
    int dst = clampi(ld_idx(ei, *iflag, (size_t)E + e), N - 1);
    attn_out[t] = __expf(scores[t]) / (segsum[(size_t)dst * 4 + h] + 1e-9f);
}

extern "C" void kernel_launch(void* const* d_in, const int* in_sizes, int n_in,
                              void* d_out, int out_size, void* d_ws, size_t ws_size,
                              hipStream_t stream)
{
    const float* x  = (const float*)d_in[0];
    const int* ei   = (const int*)d_in[1];
    const float* W0 = (const float*)d_in[2];
    const float* W1 = (const float*)d_in[3];
    const float* W2 = (const float*)d_in[4];
    const float* av = (const float*)d_in[5];
    const int N = in_sizes[0] / 128;
    const int E = in_sizes[1] / 2;

    // d_out fp32 (N*128 + E*4 floats):
    //   lo [0..N*128)     : hd f32 scratch -> out_sum (gather: row wid read-then-write, no race)
    //   hi [N*128..+E*4)  : hs fp16 (12.8MB) | sorted (6.4MB) -> attn f32 (final, overwrites both)
    float* out_f = (float*)d_out;
    float* hd = out_f;
    float* out_sum = out_f;
    unsigned short* hs = (unsigned short*)(out_f + (size_t)N * 128);
    int* sorted = (int*)(hs + (size_t)N * 128);
    float* attn_out = out_f + (size_t)N * 128;

    // ws (~38 MB): hv fp16 [N*128] | scores f32 [E*4] | segsum f32 [N*4]
    //            | cursor int [N] | deg int [N] | offs int [N+1] | iflag | bsum[<=256]
    unsigned short* hv = (unsigned short*)d_ws;
    float* scores = (float*)(hv + (size_t)N * 128);
    float* segsum = scores + (size_t)E * 4;
    int* cursor = (int*)(segsum + (size_t)N * 4);
    int* deg = cursor + N;
    int* offs = deg + N;
    int* iflag = offs + (N + 1);
    int* bsum = iflag + 1;

    const int NB = (N + 1023) / 1024;  // 49 for N=50000 (must be <= 256)

    detect_kernel<<<1, 256, 0, stream>>>(ei, iflag);
    init_kernel<<<(N + 255) / 256, 256, 0, stream>>>(deg, cursor, N);
    gemm3_kernel<<<(N + 31) / 32, 256, 0, stream>>>(x, W0, W1, W2, hs, hd, hv, N);
    hist_kernel<<<(E + 255) / 256, 256, 0, stream>>>(ei, iflag, deg, N, E);
    scanA_kernel<<<NB, 256, 0, stream>>>(deg, offs, bsum, N);
    scanB_kernel<<<1, 256, 0, stream>>>(bsum, NB);
    scanC_kernel<<<(N + 255) / 256, 256, 0, stream>>>(offs, bsum, N);
    fill_kernel<<<(E + 255) / 256, 256, 0, stream>>>(ei, iflag, offs, cursor, sorted, N, E);
    gather_fused_kernel<<<(N + 3) / 4, 256, 0, stream>>>(
        ei, iflag, offs, sorted, hs, hd, av, hv, scores, out_sum, segsum, N, E);
    attn_write_kernel<<<(E * 4 + 255) / 256, 256, 0, stream>>>(
        ei, iflag, scores, segsum, attn_out, N, E);
}

// Round 2
// 486.206 us; speedup vs baseline: 2.0853x; 1.1516x over previous
//
#include <hip/hip_runtime.h>

#define LEAKY 0.2f

// ---------- helpers ----------
__device__ __forceinline__ float h2f(unsigned short b) {
    union { unsigned short u; _Float16 h; } c; c.u = b; return (float)c.h;
}
__device__ __forceinline__ unsigned short f2h(float f) {
    union { unsigned short u; _Float16 h; } c; c.h = (_Float16)f; return c.u;
}
__device__ __forceinline__ void h4w(unsigned wx, unsigned wy, float& a, float& b, float& c, float& d) {
    a = h2f((unsigned short)(wx & 0xFFFF)); b = h2f((unsigned short)(wx >> 16));
    c = h2f((unsigned short)(wy & 0xFFFF)); d = h2f((unsigned short)(wy >> 16));
}
__device__ __forceinline__ int clampi(int v, int hi) { return v < 0 ? 0 : (v > hi ? hi : v); }
__device__ __forceinline__ int ld_idx(const int* __restrict__ ei, int is64, size_t pos) {
    return is64 ? ei[pos * 2] : ei[pos];
}

// ---- detect int64 vs int32 edge_index (odd 32-bit words all zero => int64) ----
__global__ __launch_bounds__(256) void detect_kernel(const int* __restrict__ ei, int* flag) {
    __shared__ int nz;
    if (threadIdx.x == 0) nz = 0;
    __syncthreads();
    if (ei[2 * threadIdx.x + 1] != 0) atomicOr(&nz, 1);
    __syncthreads();
    if (threadIdx.x == 0) *flag = (nz == 0) ? 1 : 0;
}

// ---- init: zero degree histogram and CSR fill cursors ----
__global__ __launch_bounds__(256) void init_kernel(int* __restrict__ deg,
                                                   int* __restrict__ cursor, int N) {
    int t = blockIdx.x * 256 + threadIdx.x;
    if (t < N) { deg[t] = 0; cursor[t] = 0; }
}

// ---- 3 GEMMs: x[N,128] @ W[128,128] -> comb fp16 (hs|hv interleaved), hd f32 ----
// comb layout: per (node, le) a 16B quad: [hs 4xfp16 | hv 4xfp16]
__global__ __launch_bounds__(256) void gemm3_kernel(
    const float* __restrict__ x,
    const float* __restrict__ W0, const float* __restrict__ W1, const float* __restrict__ W2,
    uint2* __restrict__ comb, float* __restrict__ o_hd, int N)
{
    __shared__ float Ws[128 * 128];  // 64 KB
    __shared__ float Xs[32 * 128];   // 16 KB
    const int t = threadIdx.x;
    const int row0 = blockIdx.x * 32;

    #pragma unroll
    for (int it = 0; it < 4; ++it) {
        int idx = t + it * 256;
        int r = idx >> 5, c = (idx & 31) * 4;
        float4 v = (row0 + r < N) ? *(const float4*)&x[(size_t)(row0 + r) * 128 + c]
                                  : make_float4(0.f, 0.f, 0.f, 0.f);
        *(float4*)&Xs[r * 128 + c] = v;
    }

    const int rg = t >> 5;
    const int cg = t & 31;

    for (int w = 0; w < 3; ++w) {
        const float* Wp = (w == 0) ? W0 : ((w == 1) ? W1 : W2);
        __syncthreads();
        #pragma unroll
        for (int it = 0; it < 16; ++it) {
            int idx = t + it * 256;
            *(float4*)&Ws[idx * 4] = *(const float4*)&Wp[(size_t)idx * 4];
        }
        __syncthreads();

        float acc[4][4] = {};
        for (int k = 0; k < 128; k += 4) {
            float4 a[4], b[4];
            #pragma unroll
            for (int i = 0; i < 4; i++) a[i] = *(const float4*)&Xs[(4 * rg + i) * 128 + k];
            #pragma unroll
            for (int j = 0; j < 4; j++) b[j] = *(const float4*)&Ws[(k + j) * 128 + 4 * cg];
            #pragma unroll
            for (int i = 0; i < 4; i++) {
                acc[i][0] += a[i].x * b[0].x + a[i].y * b[1].x + a[i].z * b[2].x + a[i].w * b[3].x;
                acc[i][1] += a[i].x * b[0].y + a[i].y * b[1].y + a[i].z * b[2].y + a[i].w * b[3].y;
                acc[i][2] += a[i].x * b[0].z + a[i].y * b[1].z + a[i].z * b[2].z + a[i].w * b[3].z;
                acc[i][3] += a[i].x * b[0].w + a[i].y * b[1].w + a[i].z * b[2].w + a[i].w * b[3].w;
            }
        }
        #pragma unroll
        for (int i = 0; i < 4; i++) {
            int gr = row0 + 4 * rg + i;
            if (gr >= N) continue;
            if (w == 1) {
                *(float4*)&o_hd[(size_t)gr * 128 + 4 * cg] =
                    make_float4(acc[i][0], acc[i][1], acc[i][2], acc[i][3]);
            } else {
                unsigned p0 = f2h(acc[i][0]) | ((unsigned)f2h(acc[i][1]) << 16);
                unsigned p1 = f2h(acc[i][2]) | ((unsigned)f2h(acc[i][3]) << 16);
                // hs -> slot 0, hv -> slot 1 of the 16B quad
                comb[((size_t)gr * 32 + cg) * 2 + (w == 0 ? 0 : 1)] = make_uint2(p0, p1);
            }
        }
    }
}

// ---- CSR build: histogram of dst ----
__global__ __launch_bounds__(256) void hist_kernel(
    const int* __restrict__ ei, const int* __restrict__ iflag,
    int* __restrict__ deg, int N, int E)
{
    int t = blockIdx.x * 256 + threadIdx.x;
    if (t >= E) return;
    int dst = clampi(ld_idx(ei, *iflag, (size_t)E + t), N - 1);
    atomicAdd(&deg[dst], 1);
}

// ---- multi-block exclusive scan: A) per-block (1024 elems) scan + block sums ----
__global__ __launch_bounds__(256) void scanA_kernel(
    const int* __restrict__ deg, int* __restrict__ offs, int* __restrict__ bsum, int N)
{
    __shared__ int buf[256];
    const int b = blockIdx.x;
    const int t = threadIdx.x;
    const int base = b * 1024 + t * 4;
    int v0 = (base + 0 < N) ? deg[base + 0] : 0;
    int v1 = (base + 1 < N) ? deg[base + 1] : 0;
    int v2 = (base + 2 < N) ? deg[base + 2] : 0;
    int v3 = (base + 3 < N) ? deg[base + 3] : 0;
    int tsum = v0 + v1 + v2 + v3;
    buf[t] = tsum;
    __syncthreads();
    #pragma unroll
    for (int off = 1; off < 256; off <<= 1) {
        int xv = (t >= off) ? buf[t - off] : 0;
        __syncthreads();
        buf[t] += xv;
        __syncthreads();
    }
    int p = buf[t] - tsum;  // exclusive prefix within block
    p += v0; if (base + 0 < N) offs[base + 1] = p;
    p += v1; if (base + 1 < N) offs[base + 2] = p;
    p += v2; if (base + 2 < N) offs[base + 3] = p;
    p += v3; if (base + 3 < N) offs[base + 4] = p;
    if (t == 255) bsum[b] = buf[255];
    if (b == 0 && t == 0) offs[0] = 0;
}

// ---- B) single-block exclusive scan of block sums (NB <= 256) ----
__global__ __launch_bounds__(256) void scanB_kernel(int* __restrict__ bsum, int NB)
{
    __shared__ int buf[256];
    const int t = threadIdx.x;
    int v = (t < NB) ? bsum[t] : 0;
    buf[t] = v;
    __syncthreads();
    #pragma unroll
    for (int off = 1; off < 256; off <<= 1) {
        int xv = (t >= off) ? buf[t - off] : 0;
        __syncthreads();
        buf[t] += xv;
        __syncthreads();
    }
    if (t < NB) bsum[t] = buf[t] - v;  // exclusive
}

// ---- C) add block offsets ----
__global__ __launch_bounds__(256) void scanC_kernel(
    int* __restrict__ offs, const int* __restrict__ bsum, int N)
{
    int i = blockIdx.x * 256 + threadIdx.x;
    if (i < N) offs[i + 1] += bsum[i >> 10];
}

// ---- CSR fill: sorted2[offs[dst] + cursor[dst]++] = {src, edge id} ----
// Storing src here removes the dependent random ei[eid] load from the gather loop.
__global__ __launch_bounds__(256) void fill_kernel(
    const int* __restrict__ ei, const int* __restrict__ iflag,
    const int* __restrict__ offs, int* __restrict__ cursor,
    int2* __restrict__ sorted2, int N, int E)
{
    int t = blockIdx.x * 256 + threadIdx.x;
    if (t >= E) return;
    int is64 = *iflag;
    int src = clampi(ld_idx(ei, is64, (size_t)t), N - 1);
    int dst = clampi(ld_idx(ei, is64, (size_t)E + t), N - 1);
    int pos = offs[dst] + atomicAdd(&cursor[dst], 1);
    sorted2[pos] = make_int2(src, t);
}

// ---- fused: edge scores + softmax denom + weighted aggregation ----
// One 64-lane wave per dst node. Per edge: ONE 16B gather (comb = hs|hv interleaved)
// + an 8B broadcast CSR read. Chain: sorted2 -> comb (2 levels, was 3).
// 2-level software pipeline: indices 2 iters ahead, comb data 1 iter ahead.
__global__ __launch_bounds__(256) void gather_fused_kernel(
    const int* __restrict__ offs, const int2* __restrict__ sorted2,
    const uint4* __restrict__ comb, const float* __restrict__ hd,
    const float* __restrict__ av,
    float* __restrict__ scores, float* __restrict__ out,
    float* __restrict__ segsum, int N)
{
    int wid = (int)(((size_t)blockIdx.x * 256 + threadIdx.x) >> 6);  // dst node
    if (wid >= N) return;
    int lane = threadIdx.x & 63;
    int sub = lane >> 5;   // half-wave 0/1 splits the edge list
    int le = lane & 31;
    int h = le >> 3;
    int beg = offs[wid], end = offs[wid + 1];

    float4 d4 = *(const float4*)&hd[(size_t)wid * 128 + le * 4];
    float4 a4 = *(const float4*)&av[le * 4];

    float sum = 0.f;
    float a0 = 0.f, a1 = 0.f, a2 = 0.f, a3 = 0.f;

    int j = beg + sub;
    int2 se0 = make_int2(0, 0), se1 = make_int2(0, 0);
    uint4 c0 = make_uint4(0, 0, 0, 0);
    if (j < end)     se0 = sorted2[j];
    if (j + 2 < end) se1 = sorted2[j + 2];
    if (j < end)     c0 = comb[(size_t)se0.x * 32 + le];

    while (j < end) {
        int jn = j + 2;
        int2 se2 = make_int2(0, 0);
        uint4 c1 = make_uint4(0, 0, 0, 0);
        if (jn + 2 < end) se2 = sorted2[jn + 2];
        if (jn < end)     c1 = comb[(size_t)se1.x * 32 + le];

        float s0, s1, s2, s3, v0, v1, v2, v3;
        h4w(c0.x, c0.y, s0, s1, s2, s3);   // hs
        h4w(c0.z, c0.w, v0, v1, v2, v3);   // hv
        float m, s = 0.f;
        m = s0 + d4.x; m = (m > 0.f) ? m : LEAKY * m; s += m * a4.x;
        m = s1 + d4.y; m = (m > 0.f) ? m : LEAKY * m; s += m * a4.y;
        m = s2 + d4.z; m = (m > 0.f) ? m : LEAKY * m; s += m * a4.z;
        m = s3 + d4.w; m = (m > 0.f) ? m : LEAKY * m; s += m * a4.w;
        s += __shfl_xor(s, 1);
        s += __shfl_xor(s, 2);
        s += __shfl_xor(s, 4);
        if ((le & 7) == 0) scores[(size_t)se0.y * 4 + h] = s;
        float w = __expf(s);   // |score| << 87, fp32 exp safe without max-shift
        sum += w;
        a0 += w * v0; a1 += w * v1; a2 += w * v2; a3 += w * v3;

        j = jn; se0 = se1; se1 = se2; c0 = c1;
    }
    sum += __shfl_xor(sum, 32);
    a0 += __shfl_xor(a0, 32); a1 += __shfl_xor(a1, 32);
    a2 += __shfl_xor(a2, 32); a3 += __shfl_xor(a3, 32);
    float inv = 1.f / (sum + 1e-9f);
    if (sub == 0) {
        *(float4*)&out[(size_t)wid * 128 + le * 4] =
            make_float4(a0 * inv, a1 * inv, a2 * inv, a3 * inv);
        if ((le & 7) == 0) segsum[(size_t)wid * 4 + h] = sum;
    }
}

// ---- attn output: transform scores -> attn IN PLACE (coalesced, runs last) ----
__global__ __launch_bounds__(256) void attn_write_kernel(
    const int* __restrict__ ei, const int* __restrict__ iflag,
    float* sc, const float* __restrict__ segsum, int N, int E)
{
    int t = blockIdx.x * 256 + threadIdx.x;
    if (t >= E * 4) return;
    int e = t >> 2, h = t & 3;
    int dst = clampi(ld_idx(ei, *iflag, (size_t)E + e), N - 1);
    sc[t] = __expf(sc[t]) / (segsum[(size_t)dst * 4 + h] + 1e-9f);
}

extern "C" void kernel_launch(void* const* d_in, const int* in_sizes, int n_in,
                              void* d_out, int out_size, void* d_ws, size_t ws_size,
                              hipStream_t stream)
{
    const float* x  = (const float*)d_in[0];
    const int* ei   = (const int*)d_in[1];
    const float* W0 = (const float*)d_in[2];
    const float* W1 = (const float*)d_in[3];
    const float* W2 = (const float*)d_in[4];
    const float* av = (const float*)d_in[5];
    const int N = in_sizes[0] / 128;
    const int E = in_sizes[1] / 2;

    // d_out fp32 (N*128 + E*4 floats):
    //   lo [0..N*128)     : hd f32 scratch -> out_sum (gather: row wid read-then-write, no race)
    //   hi [N*128..+E*4)  : scores f32 (gather writes) -> attn f32 IN PLACE (final)
    float* out_f = (float*)d_out;
    float* hd = out_f;
    float* out_sum = out_f;
    float* scores = out_f + (size_t)N * 128;

    // ws (~39.8 MB): comb fp16 [N*32 uint4, 25.6MB] | sorted2 int2 [E, 12.8MB]
    //              | segsum f32 [N*4] | cursor | deg | offs | iflag | bsum[<=256]
    uint4* comb = (uint4*)d_ws;
    int2* sorted2 = (int2*)(comb + (size_t)N * 32);
    float* segsum = (float*)(sorted2 + (size_t)E);
    int* cursor = (int*)(segsum + (size_t)N * 4);
    int* deg = cursor + N;
    int* offs = deg + N;
    int* iflag = offs + (N + 1);
    int* bsum = iflag + 1;

    const int NB = (N + 1023) / 1024;  // 49 for N=50000 (must be <= 256)

    detect_kernel<<<1, 256, 0, stream>>>(ei, iflag);
    init_kernel<<<(N + 255) / 256, 256, 0, stream>>>(deg, cursor, N);
    gemm3_kernel<<<(N + 31) / 32, 256, 0, stream>>>(x, W0, W1, W2, (uint2*)comb, hd, N);
    hist_kernel<<<(E + 255) / 256, 256, 0, stream>>>(ei, iflag, deg, N, E);
    scanA_kernel<<<NB, 256, 0, stream>>>(deg, offs, bsum, N);
    scanB_kernel<<<1, 256, 0, stream>>>(bsum, NB);
    scanC_kernel<<<(N + 255) / 256, 256, 0, stream>>>(offs, bsum, N);
    fill_kernel<<<(E + 255) / 256, 256, 0, stream>>>(ei, iflag, offs, cursor, sorted2, N, E);
    gather_fused_kernel<<<(N + 3) / 4, 256, 0, stream>>>(
        offs, sorted2, comb, hd, av, scores, out_sum, segsum, N);
    attn_write_kernel<<<(E * 4 + 255) / 256, 256, 0, stream>>>(
        ei, iflag, scores, segsum, N, E);
}